// Round 9
// baseline (239.224 us; speedup 1.0000x reference)
//
#include <hip/hip_runtime.h>
#include <hip/hip_bf16.h>

// MHA block: x[4096,1024] fp32; Wq/Wk/Wv/Wo [1024,1024] fp32.
// R9: QKV GEMM + casts reverted to R6 (128x64 ROUTE-1 gemm_lds — R8's
// 128x128 tile regressed). Attention K/V LDS double-buffered: R6 issued
// global_load_lds immediately before the consuming barrier, exposing full
// load latency every step; now stage(s+1) is issued right after the barrier
// and drains one full compute phase later.

typedef __bf16 bf16_t;
typedef __bf16 bf16x8 __attribute__((ext_vector_type(8)));
typedef __bf16 bf16x4 __attribute__((ext_vector_type(4)));
typedef float f32x4 __attribute__((ext_vector_type(4)));

#define D_MODEL 1024
#define SEQ 4096
#define HEADS 16
#define DK 64
#define QSCALE 0.1803368801111204f  // log2(e)/8

// ---------------- casts fp32 -> bf16 ----------------
__global__ void cast_kernel(const float* __restrict__ in, bf16_t* __restrict__ out, int n) {
    int i = (blockIdx.x * blockDim.x + threadIdx.x) * 4;
    if (i < n) {
        float4 v = *(const float4*)(in + i);
        bf16x4 o;
        o[0] = (bf16_t)v.x; o[1] = (bf16_t)v.y; o[2] = (bf16_t)v.z; o[3] = (bf16_t)v.w;
        *(bf16x4*)(out + i) = o;
    }
}

__global__ void cast4_kernel(const float* __restrict__ a, const float* __restrict__ b,
                             const float* __restrict__ c, const float* __restrict__ d,
                             bf16_t* __restrict__ out) {
    int gi = blockIdx.x * blockDim.x + threadIdx.x;
    int which = gi >> 18;
    int i = (gi & 0x3FFFF) * 4;
    const float* src = which == 0 ? a : which == 1 ? b : which == 2 ? c : d;
    float4 v = *(const float4*)(src + i);
    bf16x4 o;
    o[0] = (bf16_t)v.x; o[1] = (bf16_t)v.y; o[2] = (bf16_t)v.z; o[3] = (bf16_t)v.w;
    *(bf16x4*)(out + (size_t)which * D_MODEL * D_MODEL + i) = o;
}

__device__ __forceinline__ void g2l16(const bf16_t* g, bf16_t* l) {
    __builtin_amdgcn_global_load_lds(
        (const __attribute__((address_space(1))) void*)g,
        (__attribute__((address_space(3))) void*)l, 16, 0, 0);
}

// ---------------- LDS-staged NT GEMM (R6 version) ----------------
template <int ROUTE>
__global__ __launch_bounds__(256, 4) void gemm_lds(const bf16_t* __restrict__ A,
                                                   const bf16_t* __restrict__ B,
                                                   void* __restrict__ out0,
                                                   void* __restrict__ out1,
                                                   void* __restrict__ out2,
                                                   int M, int N, int K) {
    __shared__ __align__(16) bf16_t As[128 * 64];
    __shared__ __align__(16) bf16_t Bs[64 * 64];

    const int tid = threadIdx.x;
    const int lane = tid & 63;
    const int wave = tid >> 6;
    const int l15 = lane & 15;
    const int lg  = lane >> 4;
    const int m0 = blockIdx.y * 128;
    const int n0 = blockIdx.x * 64;
    const int wm = (wave >> 1) * 64;
    const int wn = (wave & 1) * 32;

    const bf16_t* aSrc[4]; bf16_t* aDst[4];
#pragma unroll
    for (int it = 0; it < 4; it++) {
        int c = it * 256 + tid;
        int row = c >> 3, cc = (c & 7) ^ (row & 7);
        aSrc[it] = A + (size_t)(m0 + row) * K + cc * 8;
        aDst[it] = As + c * 8;
    }
    const bf16_t* bSrc[2]; bf16_t* bDst[2];
#pragma unroll
    for (int it = 0; it < 2; it++) {
        int c = it * 256 + tid;
        int row = c >> 3, cc = (c & 7) ^ (row & 7);
        bSrc[it] = B + (size_t)(n0 + row) * K + cc * 8;
        bDst[it] = Bs + c * 8;
    }

    int aoff[2][4], boff[2][2];
#pragma unroll
    for (int kk = 0; kk < 2; kk++) {
#pragma unroll
        for (int i = 0; i < 4; i++) {
            int row = wm + i * 16 + l15;
            aoff[kk][i] = row * 64 + (((kk << 2) | lg) ^ (row & 7)) * 8;
        }
#pragma unroll
        for (int j = 0; j < 2; j++) {
            int row = wn + j * 16 + l15;
            boff[kk][j] = row * 64 + (((kk << 2) | lg) ^ (row & 7)) * 8;
        }
    }

    f32x4 acc[4][2];
#pragma unroll
    for (int i = 0; i < 4; i++)
#pragma unroll
        for (int j = 0; j < 2; j++) acc[i][j] = f32x4{0.f, 0.f, 0.f, 0.f};

    for (int k0 = 0; k0 < K; k0 += 64) {
#pragma unroll
        for (int it = 0; it < 4; it++) g2l16(aSrc[it] + k0, aDst[it]);
#pragma unroll
        for (int it = 0; it < 2; it++) g2l16(bSrc[it] + k0, bDst[it]);
        __syncthreads();

#pragma unroll
        for (int kk = 0; kk < 2; kk++) {
            bf16x8 af[4], bfm[2];
#pragma unroll
            for (int i = 0; i < 4; i++) af[i] = *(const bf16x8*)(As + aoff[kk][i]);
#pragma unroll
            for (int j = 0; j < 2; j++) bfm[j] = *(const bf16x8*)(Bs + boff[kk][j]);
#pragma unroll
            for (int i = 0; i < 4; i++)
#pragma unroll
                for (int j = 0; j < 2; j++)
                    acc[i][j] = __builtin_amdgcn_mfma_f32_16x16x32_bf16(af[i], bfm[j], acc[i][j], 0, 0, 0);
        }
        __syncthreads();
    }

    const int ng = n0 + wn;
    if (ROUTE == 0) {
        float* C = (float*)out0;
#pragma unroll
        for (int i = 0; i < 4; i++)
#pragma unroll
            for (int r = 0; r < 4; r++) {
                int m = m0 + wm + i * 16 + lg * 4 + r;
                float* crow = C + (size_t)m * N + ng;
#pragma unroll
                for (int j = 0; j < 2; j++) crow[j * 16 + l15] = acc[i][j][r];
            }
    } else {
        if (ng < 2048) {
            const bool isQ = (ng < 1024);
            const float sc = isQ ? QSCALE : 1.0f;
            bf16_t* dst = isQ ? (bf16_t*)out0 : (bf16_t*)out1;
            int nn = ng & 1023;
#pragma unroll
            for (int i = 0; i < 4; i++)
#pragma unroll
                for (int r = 0; r < 4; r++) {
                    int m = m0 + wm + i * 16 + lg * 4 + r;
                    bf16_t* crow = dst + (size_t)m * D_MODEL + nn;
#pragma unroll
                    for (int j = 0; j < 2; j++) crow[j * 16 + l15] = (bf16_t)(acc[i][j][r] * sc);
                }
        } else {
            bf16_t* Vt = (bf16_t*)out2;
#pragma unroll
            for (int i = 0; i < 4; i++)
#pragma unroll
                for (int j = 0; j < 2; j++) {
                    int vcol = ng - 2048 + j * 16 + l15;
                    int m = m0 + wm + i * 16 + lg * 4;
                    bf16x4 v4;
#pragma unroll
                    for (int r = 0; r < 4; r++) v4[r] = (bf16_t)acc[i][j][r];
                    *(bf16x4*)(Vt + (size_t)vcol * SEQ + m) = v4;
                }
        }
    }
}

// ---------------- attention: S^T trick, exp2, K=32 PV, LDS double-buffer ----
__global__ __launch_bounds__(256) void attn_kernel(const bf16_t* __restrict__ Q,
                                                   const bf16_t* __restrict__ Km,
                                                   const bf16_t* __restrict__ Vt,
                                                   bf16_t* __restrict__ O) {
    const int tid = threadIdx.x;
    const int lane = tid & 63;
    const int wave = tid >> 6;
    const int l15 = lane & 15;
    const int lg  = lane >> 4;
    const int bid = blockIdx.x;
    const int h    = (bid & 7) * 2 + ((bid >> 3) & 1);
    const int qblk = bid >> 4;
    const int q0 = qblk * 128;
    const int hoff = h * DK;

    __shared__ union {
        struct { __align__(16) bf16_t K[2][64 * 64]; __align__(16) bf16_t V[2][64 * 64]; } kv;
        __align__(16) bf16_t Ot[128][72];
    } sm;

    bf16x8 qf[2][2];
#pragma unroll
    for (int t = 0; t < 2; t++)
#pragma unroll
        for (int c = 0; c < 2; c++)
            qf[t][c] = *(const bf16x8*)(Q + (size_t)(q0 + wave * 32 + t * 16 + l15) * D_MODEL
                                        + hoff + c * 32 + lg * 8);

    f32x4 oacc[2][4], lfrag[2];
#pragma unroll
    for (int t = 0; t < 2; t++) {
        lfrag[t] = f32x4{0.f, 0.f, 0.f, 0.f};
#pragma unroll
        for (int dt = 0; dt < 4; dt++) oacc[t][dt] = f32x4{0.f, 0.f, 0.f, 0.f};
    }

    bf16x8 ones8;
#pragma unroll
    for (int j = 0; j < 8; j++) ones8[j] = (bf16_t)1.0f;

    const bf16_t* kSrc[2]; const bf16_t* vSrc[2];
#pragma unroll
    for (int it = 0; it < 2; it++) {
        int c = it * 256 + tid;
        int row = c >> 3, dc = (c & 7) ^ (row & 7);
        kSrc[it] = Km + (size_t)row * D_MODEL + hoff + dc * 8;
        vSrc[it] = Vt + (size_t)(hoff + row) * SEQ + dc * 8;
    }

    int kOff[4][2], vOff[2][2][4];
#pragma unroll
    for (int kt = 0; kt < 4; kt++)
#pragma unroll
        for (int c = 0; c < 2; c++) {
            int row = kt * 16 + l15;
            kOff[kt][c] = row * 64 + (((c * 4 + lg) ^ (row & 7)) * 8);
        }
#pragma unroll
    for (int kp = 0; kp < 2; kp++)
#pragma unroll
        for (int hf = 0; hf < 2; hf++)
#pragma unroll
            for (int dt = 0; dt < 4; dt++) {
                int row = dt * 16 + l15;
                vOff[kp][hf][dt] = row * 64 + (((kp * 4 + hf * 2 + (lg >> 1)) ^ (row & 7)) * 8)
                                   + (lg & 1) * 4;
            }

    // prologue: stage step 0 into buffer 0
#pragma unroll
    for (int it = 0; it < 2; it++) {
        g2l16(kSrc[it], &sm.kv.K[0][(it * 256 + tid) * 8]);
        g2l16(vSrc[it], &sm.kv.V[0][(it * 256 + tid) * 8]);
    }

    for (int s = 0; s < SEQ / 64; s++) {
        const int cur = s & 1;
        __syncthreads();  // drains stage(s) (in flight since last compute phase)

        if (s + 1 < SEQ / 64) {
            const int nxt = cur ^ 1;
#pragma unroll
            for (int it = 0; it < 2; it++) {
                g2l16(kSrc[it] + (size_t)(s + 1) * 64 * D_MODEL, &sm.kv.K[nxt][(it * 256 + tid) * 8]);
                g2l16(vSrc[it] + (s + 1) * 64,                   &sm.kv.V[nxt][(it * 256 + tid) * 8]);
            }
        }

        const bf16_t* Kb = sm.kv.K[cur];
        const bf16_t* Vb = sm.kv.V[cur];

#pragma unroll
        for (int kp = 0; kp < 2; kp++) {
            f32x4 st[2][2];
#pragma unroll
            for (int sub = 0; sub < 2; sub++) {
                const int kt = kp * 2 + sub;
                const bf16x8 kf0 = *(const bf16x8*)(Kb + kOff[kt][0]);
                const bf16x8 kf1 = *(const bf16x8*)(Kb + kOff[kt][1]);
#pragma unroll
                for (int t = 0; t < 2; t++) {
                    f32x4 a = f32x4{0.f, 0.f, 0.f, 0.f};
                    a = __builtin_amdgcn_mfma_f32_16x16x32_bf16(kf0, qf[t][0], a, 0, 0, 0);
                    a = __builtin_amdgcn_mfma_f32_16x16x32_bf16(kf1, qf[t][1], a, 0, 0, 0);
                    st[t][sub] = a;
                }
            }

            bf16x8 pbig[2];
#pragma unroll
            for (int t = 0; t < 2; t++)
#pragma unroll
                for (int r = 0; r < 4; r++) {
                    pbig[t][r]     = (bf16_t)__builtin_amdgcn_exp2f(st[t][0][r]);
                    pbig[t][r + 4] = (bf16_t)__builtin_amdgcn_exp2f(st[t][1][r]);
                }

            lfrag[0] = __builtin_amdgcn_mfma_f32_16x16x32_bf16(ones8, pbig[0], lfrag[0], 0, 0, 0);
            lfrag[1] = __builtin_amdgcn_mfma_f32_16x16x32_bf16(ones8, pbig[1], lfrag[1], 0, 0, 0);

#pragma unroll
            for (int dt = 0; dt < 4; dt++) {
                const bf16x4 v0 = *(const bf16x4*)(Vb + vOff[kp][0][dt]);
                const bf16x4 v1 = *(const bf16x4*)(Vb + vOff[kp][1][dt]);
                bf16x8 vf;
#pragma unroll
                for (int j = 0; j < 4; j++) { vf[j] = v0[j]; vf[j + 4] = v1[j]; }
                oacc[0][dt] = __builtin_amdgcn_mfma_f32_16x16x32_bf16(vf, pbig[0], oacc[0][dt], 0, 0, 0);
                oacc[1][dt] = __builtin_amdgcn_mfma_f32_16x16x32_bf16(vf, pbig[1], oacc[1][dt], 0, 0, 0);
            }
        }
    }
    __syncthreads();  // all reads of kv done before Ot overwrites the union

#pragma unroll
    for (int t = 0; t < 2; t++) {
        float inv = 1.f / lfrag[t][0];
        const int qrow = wave * 32 + t * 16 + l15;
#pragma unroll
        for (int dt = 0; dt < 4; dt++)
#pragma unroll
            for (int r = 0; r < 4; r++)
                sm.Ot[qrow][dt * 16 + lg * 4 + r] = (bf16_t)(oacc[t][dt][r] * inv);
    }
    __syncthreads();

    {
        const int row = tid >> 1;
        const int half = tid & 1;
        bf16_t* orow = O + (size_t)(q0 + row) * D_MODEL + hoff + half * 32;
#pragma unroll
        for (int m = 0; m < 4; m++)
            *(bf16x8*)(orow + m * 8) = *(const bf16x8*)(&sm.Ot[row][half * 32 + m * 8]);
    }
}

// ---------------- launcher ----------------
extern "C" void kernel_launch(void* const* d_in, const int* in_sizes, int n_in,
                              void* d_out, int out_size, void* d_ws, size_t ws_size,
                              hipStream_t stream) {
    const float* x  = (const float*)d_in[0];
    const float* Wq = (const float*)d_in[1];
    const float* Wk = (const float*)d_in[2];
    const float* Wv = (const float*)d_in[3];
    const float* Wo = (const float*)d_in[4];
    float* out = (float*)d_out;

    char* ws = (char*)d_ws;
    bf16_t* xb  = (bf16_t*)(ws);
    bf16_t* wqb = (bf16_t*)(ws + (8u  << 20));
    bf16_t* wob = (bf16_t*)(ws + (14u << 20));
    bf16_t* Qb  = (bf16_t*)(ws + (16u << 20));
    bf16_t* Kb  = (bf16_t*)(ws + (24u << 20));
    bf16_t* Vtb = (bf16_t*)(ws + (32u << 20));
    bf16_t* Ab  = (bf16_t*)(ws + (40u << 20));

    const int nX = SEQ * D_MODEL;
    cast_kernel<<<nX / 4 / 256, 256, 0, stream>>>(x, xb, nX);
    cast4_kernel<<<4 * 1024, 256, 0, stream>>>(Wq, Wk, Wv, Wo, wqb);

    gemm_lds<1><<<dim3(3 * D_MODEL / 64, SEQ / 128), 256, 0, stream>>>(
        xb, wqb, Qb, Kb, Vtb, SEQ, 3 * D_MODEL, D_MODEL);

    attn_kernel<<<512, 256, 0, stream>>>(Qb, Kb, Vtb, Ab);

    gemm_lds<0><<<dim3(D_MODEL / 64, SEQ / 128), 256, 0, stream>>>(
        Ab, wob, out, nullptr, nullptr, SEQ, D_MODEL, D_MODEL);
}

// Round 10
// 218.212 us; speedup vs baseline: 1.0963x; 1.0963x over previous
//
#include <hip/hip_runtime.h>
#include <hip/hip_bf16.h>

// MHA block: x[4096,1024] fp32; Wq/Wk/Wv/Wo [1024,1024] fp32.
// R10: attention VALU diet #2.
//  (a) Schraudolph exp2 -> bf16 bits: p = 2^st approximated by
//      bits = (int)(st*128 + 16250.99)  (bf16 = exp<<7|mant; mantissa-linear,
//      +-3% rel err, pseudo-random across keys; softmax-consistent since the
//      same p feeds both PV and the l-sum). Replaces quarter-rate v_exp +
//      scalar cvt + element packing.
//  (b) V^T stored key-INTERLEAVED (perm within 32-key blocks, applied in the
//      V projection epilogue) so the PV A-fragment is ONE ds_read_b128
//      (exact: key order in the softmax sum is arbitrary).
// Keeps: R9 K/V LDS double-buffer, R6 GEMMs/casts, S^T trick, MFMA l-sums.

typedef __bf16 bf16_t;
typedef __bf16 bf16x8 __attribute__((ext_vector_type(8)));
typedef __bf16 bf16x4 __attribute__((ext_vector_type(4)));
typedef float f32x4 __attribute__((ext_vector_type(4)));

#define D_MODEL 1024
#define SEQ 4096
#define HEADS 16
#define DK 64
#define QSCALE 0.1803368801111204f  // log2(e)/8

// ---------------- casts fp32 -> bf16 ----------------
__global__ void cast_kernel(const float* __restrict__ in, bf16_t* __restrict__ out, int n) {
    int i = (blockIdx.x * blockDim.x + threadIdx.x) * 4;
    if (i < n) {
        float4 v = *(const float4*)(in + i);
        bf16x4 o;
        o[0] = (bf16_t)v.x; o[1] = (bf16_t)v.y; o[2] = (bf16_t)v.z; o[3] = (bf16_t)v.w;
        *(bf16x4*)(out + i) = o;
    }
}

__global__ void cast4_kernel(const float* __restrict__ a, const float* __restrict__ b,
                             const float* __restrict__ c, const float* __restrict__ d,
                             bf16_t* __restrict__ out) {
    int gi = blockIdx.x * blockDim.x + threadIdx.x;
    int which = gi >> 18;
    int i = (gi & 0x3FFFF) * 4;
    const float* src = which == 0 ? a : which == 1 ? b : which == 2 ? c : d;
    float4 v = *(const float4*)(src + i);
    bf16x4 o;
    o[0] = (bf16_t)v.x; o[1] = (bf16_t)v.y; o[2] = (bf16_t)v.z; o[3] = (bf16_t)v.w;
    *(bf16x4*)(out + (size_t)which * D_MODEL * D_MODEL + i) = o;
}

__device__ __forceinline__ void g2l16(const bf16_t* g, bf16_t* l) {
    __builtin_amdgcn_global_load_lds(
        (const __attribute__((address_space(1))) void*)g,
        (__attribute__((address_space(3))) void*)l, 16, 0, 0);
}

// Schraudolph exp2 -> packed bf16x8: slots 0-3 = 2^a[r], 4-7 = 2^b[r]
__device__ __forceinline__ bf16x8 exp2_pk(const f32x4 a, const f32x4 b) {
    int v[8];
#pragma unroll
    for (int r = 0; r < 4; r++) {
        v[r]     = (int)fmaf(a[r], 128.0f, 16250.99f);
        v[r + 4] = (int)fmaf(b[r], 128.0f, 16250.99f);
    }
    union { int u[4]; bf16x8 h; } o;
#pragma unroll
    for (int p = 0; p < 4; p++) o.u[p] = v[2 * p] | (v[2 * p + 1] << 16);
    return o.h;
}

// ---------------- LDS-staged NT GEMM ----------------
// ROUTE 1: QKV split; V^T written key-interleaved (see header comment).
template <int ROUTE>
__global__ __launch_bounds__(256, 4) void gemm_lds(const bf16_t* __restrict__ A,
                                                   const bf16_t* __restrict__ B,
                                                   void* __restrict__ out0,
                                                   void* __restrict__ out1,
                                                   void* __restrict__ out2,
                                                   int M, int N, int K) {
    __shared__ __align__(16) bf16_t As[128 * 64];
    __shared__ __align__(16) bf16_t Bs[64 * 64];

    const int tid = threadIdx.x;
    const int lane = tid & 63;
    const int wave = tid >> 6;
    const int l15 = lane & 15;
    const int lg  = lane >> 4;
    const int m0 = blockIdx.y * 128;
    const int n0 = blockIdx.x * 64;
    const int wm = (wave >> 1) * 64;
    const int wn = (wave & 1) * 32;

    const bf16_t* aSrc[4]; bf16_t* aDst[4];
#pragma unroll
    for (int it = 0; it < 4; it++) {
        int c = it * 256 + tid;
        int row = c >> 3, cc = (c & 7) ^ (row & 7);
        aSrc[it] = A + (size_t)(m0 + row) * K + cc * 8;
        aDst[it] = As + c * 8;
    }
    const bf16_t* bSrc[2]; bf16_t* bDst[2];
#pragma unroll
    for (int it = 0; it < 2; it++) {
        int c = it * 256 + tid;
        int row = c >> 3, cc = (c & 7) ^ (row & 7);
        bSrc[it] = B + (size_t)(n0 + row) * K + cc * 8;
        bDst[it] = Bs + c * 8;
    }

    int aoff[2][4], boff[2][2];
#pragma unroll
    for (int kk = 0; kk < 2; kk++) {
#pragma unroll
        for (int i = 0; i < 4; i++) {
            int row = wm + i * 16 + l15;
            aoff[kk][i] = row * 64 + (((kk << 2) | lg) ^ (row & 7)) * 8;
        }
#pragma unroll
        for (int j = 0; j < 2; j++) {
            int row = wn + j * 16 + l15;
            boff[kk][j] = row * 64 + (((kk << 2) | lg) ^ (row & 7)) * 8;
        }
    }

    f32x4 acc[4][2];
#pragma unroll
    for (int i = 0; i < 4; i++)
#pragma unroll
        for (int j = 0; j < 2; j++) acc[i][j] = f32x4{0.f, 0.f, 0.f, 0.f};

    for (int k0 = 0; k0 < K; k0 += 64) {
#pragma unroll
        for (int it = 0; it < 4; it++) g2l16(aSrc[it] + k0, aDst[it]);
#pragma unroll
        for (int it = 0; it < 2; it++) g2l16(bSrc[it] + k0, bDst[it]);
        __syncthreads();

#pragma unroll
        for (int kk = 0; kk < 2; kk++) {
            bf16x8 af[4], bfm[2];
#pragma unroll
            for (int i = 0; i < 4; i++) af[i] = *(const bf16x8*)(As + aoff[kk][i]);
#pragma unroll
            for (int j = 0; j < 2; j++) bfm[j] = *(const bf16x8*)(Bs + boff[kk][j]);
#pragma unroll
            for (int i = 0; i < 4; i++)
#pragma unroll
                for (int j = 0; j < 2; j++)
                    acc[i][j] = __builtin_amdgcn_mfma_f32_16x16x32_bf16(af[i], bfm[j], acc[i][j], 0, 0, 0);
        }
        __syncthreads();
    }

    const int ng = n0 + wn;
    if (ROUTE == 0) {
        float* C = (float*)out0;
#pragma unroll
        for (int i = 0; i < 4; i++)
#pragma unroll
            for (int r = 0; r < 4; r++) {
                int m = m0 + wm + i * 16 + lg * 4 + r;
                float* crow = C + (size_t)m * N + ng;
#pragma unroll
                for (int j = 0; j < 2; j++) crow[j * 16 + l15] = acc[i][j][r];
            }
    } else {
        if (ng < 2048) {
            const bool isQ = (ng < 1024);
            const float sc = isQ ? QSCALE : 1.0f;
            bf16_t* dst = isQ ? (bf16_t*)out0 : (bf16_t*)out1;
            int nn = ng & 1023;
#pragma unroll
            for (int i = 0; i < 4; i++)
#pragma unroll
                for (int r = 0; r < 4; r++) {
                    int m = m0 + wm + i * 16 + lg * 4 + r;
                    bf16_t* crow = dst + (size_t)m * D_MODEL + nn;
#pragma unroll
                    for (int j = 0; j < 2; j++) crow[j * 16 + l15] = (bf16_t)(acc[i][j][r] * sc);
                }
        } else {
            bf16_t* Vt = (bf16_t*)out2;
#pragma unroll
            for (int i = 0; i < 4; i++)
#pragma unroll
                for (int j = 0; j < 2; j++) {
                    int vcol = ng - 2048 + j * 16 + l15;
                    int m = m0 + wm + i * 16 + lg * 4;  // multiple of 4
                    // key-interleave within 32-key block: pos = g*8 + sub*4 + r
                    int mp = (m & ~31) | (((m >> 2) & 3) << 3) | (((m >> 4) & 1) << 2);
                    bf16x4 v4;
#pragma unroll
                    for (int r = 0; r < 4; r++) v4[r] = (bf16_t)acc[i][j][r];
                    *(bf16x4*)(Vt + (size_t)vcol * SEQ + mp) = v4;
                }
        }
    }
}

// ---------------- attention: S^T, Schraudolph exp2, K=32 PV, dbuf ----------
__global__ __launch_bounds__(256) void attn_kernel(const bf16_t* __restrict__ Q,
                                                   const bf16_t* __restrict__ Km,
                                                   const bf16_t* __restrict__ Vt,
                                                   bf16_t* __restrict__ O) {
    const int tid = threadIdx.x;
    const int lane = tid & 63;
    const int wave = tid >> 6;
    const int l15 = lane & 15;
    const int lg  = lane >> 4;
    const int bid = blockIdx.x;
    const int h    = (bid & 7) * 2 + ((bid >> 3) & 1);
    const int qblk = bid >> 4;
    const int q0 = qblk * 128;
    const int hoff = h * DK;

    __shared__ union {
        struct { __align__(16) bf16_t K[2][64 * 64]; __align__(16) bf16_t V[2][64 * 64]; } kv;
        __align__(16) bf16_t Ot[128][72];
    } sm;

    bf16x8 qf[2][2];
#pragma unroll
    for (int t = 0; t < 2; t++)
#pragma unroll
        for (int c = 0; c < 2; c++)
            qf[t][c] = *(const bf16x8*)(Q + (size_t)(q0 + wave * 32 + t * 16 + l15) * D_MODEL
                                        + hoff + c * 32 + lg * 8);

    f32x4 oacc[2][4], lfrag[2];
#pragma unroll
    for (int t = 0; t < 2; t++) {
        lfrag[t] = f32x4{0.f, 0.f, 0.f, 0.f};
#pragma unroll
        for (int dt = 0; dt < 4; dt++) oacc[t][dt] = f32x4{0.f, 0.f, 0.f, 0.f};
    }

    bf16x8 ones8;
#pragma unroll
    for (int j = 0; j < 8; j++) ones8[j] = (bf16_t)1.0f;

    const bf16_t* kSrc[2]; const bf16_t* vSrc[2];
#pragma unroll
    for (int it = 0; it < 2; it++) {
        int c = it * 256 + tid;
        int row = c >> 3, dc = (c & 7) ^ (row & 7);
        kSrc[it] = Km + (size_t)row * D_MODEL + hoff + dc * 8;
        vSrc[it] = Vt + (size_t)(hoff + row) * SEQ + dc * 8;
    }

    int kOff[4][2], vOff[2][4];
#pragma unroll
    for (int kt = 0; kt < 4; kt++)
#pragma unroll
        for (int c = 0; c < 2; c++) {
            int row = kt * 16 + l15;
            kOff[kt][c] = row * 64 + (((c * 4 + lg) ^ (row & 7)) * 8);
        }
#pragma unroll
    for (int kp = 0; kp < 2; kp++)
#pragma unroll
        for (int dt = 0; dt < 4; dt++) {
            int row = dt * 16 + l15;
            // single b128: interleaved keys, column kp*32 + lg*8
            vOff[kp][dt] = row * 64 + (((kp * 4 + lg) ^ (row & 7)) * 8);
        }

    // prologue: stage step 0 into buffer 0
#pragma unroll
    for (int it = 0; it < 2; it++) {
        g2l16(kSrc[it], &sm.kv.K[0][(it * 256 + tid) * 8]);
        g2l16(vSrc[it], &sm.kv.V[0][(it * 256 + tid) * 8]);
    }

    for (int s = 0; s < SEQ / 64; s++) {
        const int cur = s & 1;
        __syncthreads();

        if (s + 1 < SEQ / 64) {
            const int nxt = cur ^ 1;
#pragma unroll
            for (int it = 0; it < 2; it++) {
                g2l16(kSrc[it] + (size_t)(s + 1) * 64 * D_MODEL, &sm.kv.K[nxt][(it * 256 + tid) * 8]);
                g2l16(vSrc[it] + (s + 1) * 64,                   &sm.kv.V[nxt][(it * 256 + tid) * 8]);
            }
        }

        const bf16_t* Kb = sm.kv.K[cur];
        const bf16_t* Vb = sm.kv.V[cur];

#pragma unroll
        for (int kp = 0; kp < 2; kp++) {
            f32x4 st[2][2];
#pragma unroll
            for (int sub = 0; sub < 2; sub++) {
                const int kt = kp * 2 + sub;
                const bf16x8 kf0 = *(const bf16x8*)(Kb + kOff[kt][0]);
                const bf16x8 kf1 = *(const bf16x8*)(Kb + kOff[kt][1]);
#pragma unroll
                for (int t = 0; t < 2; t++) {
                    f32x4 a = f32x4{0.f, 0.f, 0.f, 0.f};
                    a = __builtin_amdgcn_mfma_f32_16x16x32_bf16(kf0, qf[t][0], a, 0, 0, 0);
                    a = __builtin_amdgcn_mfma_f32_16x16x32_bf16(kf1, qf[t][1], a, 0, 0, 0);
                    st[t][sub] = a;
                }
            }

            const bf16x8 pbig0 = exp2_pk(st[0][0], st[0][1]);
            const bf16x8 pbig1 = exp2_pk(st[1][0], st[1][1]);

            lfrag[0] = __builtin_amdgcn_mfma_f32_16x16x32_bf16(ones8, pbig0, lfrag[0], 0, 0, 0);
            lfrag[1] = __builtin_amdgcn_mfma_f32_16x16x32_bf16(ones8, pbig1, lfrag[1], 0, 0, 0);

#pragma unroll
            for (int dt = 0; dt < 4; dt++) {
                const bf16x8 vf = *(const bf16x8*)(Vb + vOff[kp][dt]);
                oacc[0][dt] = __builtin_amdgcn_mfma_f32_16x16x32_bf16(vf, pbig0, oacc[0][dt], 0, 0, 0);
                oacc[1][dt] = __builtin_amdgcn_mfma_f32_16x16x32_bf16(vf, pbig1, oacc[1][dt], 0, 0, 0);
            }
        }
    }
    __syncthreads();

#pragma unroll
    for (int t = 0; t < 2; t++) {
        float inv = 1.f / lfrag[t][0];
        const int qrow = wave * 32 + t * 16 + l15;
#pragma unroll
        for (int dt = 0; dt < 4; dt++)
#pragma unroll
            for (int r = 0; r < 4; r++)
                sm.Ot[qrow][dt * 16 + lg * 4 + r] = (bf16_t)(oacc[t][dt][r] * inv);
    }
    __syncthreads();

    {
        const int row = tid >> 1;
        const int half = tid & 1;
        bf16_t* orow = O + (size_t)(q0 + row) * D_MODEL + hoff + half * 32;
#pragma unroll
        for (int m = 0; m < 4; m++)
            *(bf16x8*)(orow + m * 8) = *(const bf16x8*)(&sm.Ot[row][half * 32 + m * 8]);
    }
}

// ---------------- launcher ----------------
extern "C" void kernel_launch(void* const* d_in, const int* in_sizes, int n_in,
                              void* d_out, int out_size, void* d_ws, size_t ws_size,
                              hipStream_t stream) {
    const float* x  = (const float*)d_in[0];
    const float* Wq = (const float*)d_in[1];
    const float* Wk = (const float*)d_in[2];
    const float* Wv = (const float*)d_in[3];
    const float* Wo = (const float*)d_in[4];
    float* out = (float*)d_out;

    char* ws = (char*)d_ws;
    bf16_t* xb  = (bf16_t*)(ws);
    bf16_t* wqb = (bf16_t*)(ws + (8u  << 20));
    bf16_t* wob = (bf16_t*)(ws + (14u << 20));
    bf16_t* Qb  = (bf16_t*)(ws + (16u << 20));
    bf16_t* Kb  = (bf16_t*)(ws + (24u << 20));
    bf16_t* Vtb = (bf16_t*)(ws + (32u << 20));
    bf16_t* Ab  = (bf16_t*)(ws + (40u << 20));

    const int nX = SEQ * D_MODEL;
    cast_kernel<<<nX / 4 / 256, 256, 0, stream>>>(x, xb, nX);
    cast4_kernel<<<4 * 1024, 256, 0, stream>>>(Wq, Wk, Wv, Wo, wqb);

    gemm_lds<1><<<dim3(3 * D_MODEL / 64, SEQ / 128), 256, 0, stream>>>(
        xb, wqb, Qb, Kb, Vtb, SEQ, 3 * D_MODEL, D_MODEL);

    attn_kernel<<<512, 256, 0, stream>>>(Qb, Kb, Vtb, Ab);

    gemm_lds<0><<<dim3(D_MODEL / 64, SEQ / 128), 256, 0, stream>>>(
        Ab, wob, out, nullptr, nullptr, SEQ, D_MODEL, D_MODEL);
}